// Round 12
// baseline (352.861 us; speedup 1.0000x reference)
//
#include <hip/hip_runtime.h>
#include <math.h>

// ---------------------------------------------------------------------------
// GCN forward, CSR + 16-wide aggregation for BOTH layers.
// Algebra #1: norm = dinv[r]*dinv[c] => pre-scale features by dinv[c],
//   post-scale row sums by dinv[r].
// Algebra #2: W2 is linear => aggregate the 16-wide u = relu(.)*dinv and
//   apply W2 AFTER aggregation (64B/edge gather over a 6.4MB table).
// CSR build (hierarchical; R3/R4 lesson: no large random atomic targets):
//   k_bhist -> k_bscan -> k_bscatter -> k_bsort2, packed 32-bit pairs.
// GEMM1 history: R5-R9: per-lane row streams -> L1/L2 line-refetch (3-4x);
//   R10/R11: LDS staging fixed FETCH but __syncthreads emits s_waitcnt
//   vmcnt(0) before s_barrier -> the barrier between prefetch-issue and
//   compute DRAINED the prefetch every chunk (serialized, 118us, VALU 10%).
// R12: NO BARRIERS in the main loop. Lane (lrow,lkq) owns 8 rows x a 4-wide
//   k-slice; acc[8][16] lives in registers (no x-LDS, no inter-lane exchange
//   until the final 3-stage shfl reduce over lkq). Loads stay full-line
//   coalesced (8 rows x 128B per wave instr). W1 pre-transposed (k_w1t) and
//   staged once to 8KB LDS; 16 broadcast ds_read_b128 per chunk. Explicit
//   pf/pg register double-buffer in a 2-step loop -> compiler overlaps HBM
//   latency with compute freely.
// ---------------------------------------------------------------------------

#define BSHIFT 7          // 128 rows per bucket
#define CHUNK_E 8192      // edges per bucketing block
#define PACK_SHIFT 25
#define PACK_MASK 0x01FFFFFF

__global__ void k_detect(const int* __restrict__ ei32, int* __restrict__ flag) {
    int t = threadIdx.x;
    bool z = (ei32[2 * t + 1] == 0);
    unsigned long long m = __ballot(z);
    if (t == 0) *flag = (m == 0xFFFFFFFFFFFFFFFFULL) ? 1 : 0;
}

__global__ void k_zero(int* __restrict__ p, int n) {
    int i = blockIdx.x * blockDim.x + threadIdx.x;
    if (i < n) p[i] = 0;
}

// Transpose W1 (512x16 row-major) -> W1T (16x512): w1t[f*512+k] = W1[k*16+f]
__global__ __launch_bounds__(256) void k_w1t(
        const float* __restrict__ W1, float* __restrict__ w1t) {
    int idx = blockIdx.x * 256 + threadIdx.x;   // 0..8191
    int k = idx & 511, f = idx >> 9;
    w1t[f * 512 + k] = W1[k * 16 + f];
}

// ---------------------------------------------------------------------------
// Pass A: per-block LDS histogram of row-buckets; <=nbuck global atomics/block.
// ---------------------------------------------------------------------------
__global__ __launch_bounds__(256) void k_bhist(
        const void* __restrict__ ei, const int* __restrict__ flag,
        int* __restrict__ bcnt, int E, int nbuck) {
    __shared__ int cnt[1024];
    int tid = threadIdx.x;
    for (int i = tid; i < nbuck; i += 256) cnt[i] = 0;
    __syncthreads();
    int e0 = blockIdx.x * CHUNK_E;
    int e1 = min(E, e0 + CHUNK_E);
    bool f = (*flag) != 0;
    for (int e = e0 + tid; e < e1; e += 256) {
        int r = f ? (int)((const long long*)ei)[e] : ((const int*)ei)[e];
        atomicAdd(&cnt[r >> BSHIFT], 1);
    }
    __syncthreads();
    for (int i = tid; i < nbuck; i += 256)
        if (cnt[i]) atomicAdd(&bcnt[i], cnt[i]);
}

// ---------------------------------------------------------------------------
// Scan bucket counts -> bbase (exclusive), bcur (working copy).
// ---------------------------------------------------------------------------
__global__ __launch_bounds__(1024) void k_bscan(
        const int* __restrict__ bcnt, int* __restrict__ bbase,
        int* __restrict__ bcur, int nbuck, int E,
        int* __restrict__ row_ptr, int n) {
    __shared__ int ls[1024];
    int t = threadIdx.x;
    int v = (t < nbuck) ? bcnt[t] : 0;
    ls[t] = v; __syncthreads();
    for (int off = 1; off < 1024; off <<= 1) {
        int tmp = (t >= off) ? ls[t - off] : 0;
        __syncthreads();
        ls[t] += tmp;
        __syncthreads();
    }
    int ex = ls[t] - v;  // exclusive
    if (t < nbuck) { bbase[t] = ex; bcur[t] = ex; }
    if (t == 0) { bbase[nbuck] = E; row_ptr[n] = E; }
}

// ---------------------------------------------------------------------------
// Pass B: bucket edges into contiguous per-bucket segments (packed 32-bit).
// ---------------------------------------------------------------------------
__global__ __launch_bounds__(256) void k_bscatter(
        const void* __restrict__ ei, const int* __restrict__ flag,
        int* __restrict__ bcur, unsigned int* __restrict__ pair, int E, int nbuck) {
    __shared__ int cnt[1024];
    __shared__ int runs[1024];
    int tid = threadIdx.x;
    for (int i = tid; i < nbuck; i += 256) cnt[i] = 0;
    __syncthreads();
    int e0 = blockIdx.x * CHUNK_E;
    int e1 = min(E, e0 + CHUNK_E);
    bool f = (*flag) != 0;
    for (int e = e0 + tid; e < e1; e += 256) {
        int r = f ? (int)((const long long*)ei)[e] : ((const int*)ei)[e];
        atomicAdd(&cnt[r >> BSHIFT], 1);
    }
    __syncthreads();
    for (int i = tid; i < nbuck; i += 256) {
        int c = cnt[i];
        runs[i] = (c > 0) ? atomicAdd(&bcur[i], c) : 0;
        cnt[i] = 0;  // reuse as local cursor
    }
    __syncthreads();
    for (int e = e0 + tid; e < e1; e += 256) {
        int r, c;
        if (f) { const long long* p = (const long long*)ei; r = (int)p[e]; c = (int)p[E + e]; }
        else   { const int* p = (const int*)ei;             r = p[e];      c = p[E + e]; }
        int b = r >> BSHIFT;
        int pos = runs[b] + atomicAdd(&cnt[b], 1);
        pair[pos] = ((unsigned int)(r & 127) << PACK_SHIFT) | (unsigned int)c;
    }
}

// ---------------------------------------------------------------------------
// Pass C: one block per bucket. LDS histogram -> local exclusive scan ->
// row_ptr + dinv (fused rsqrt), then LDS-cursor scatter to csr_col.
// ---------------------------------------------------------------------------
__global__ __launch_bounds__(256) void k_bsort2(
        const unsigned int* __restrict__ pair, const int* __restrict__ bbase,
        int* __restrict__ row_ptr, float* __restrict__ dinv,
        int* __restrict__ csr_col, int n) {
    __shared__ int cnt[128];
    __shared__ int scn[128];
    __shared__ int cur[128];
    int b = blockIdx.x;
    int lo = b << BSHIFT, hi = min(n, lo + 128);
    int nr = hi - lo;
    int tid = threadIdx.x;
    if (tid < 128) cnt[tid] = 0;
    __syncthreads();
    int s = bbase[b], e = bbase[b + 1];
    for (int j = s + tid; j < e; j += 256)
        atomicAdd(&cnt[pair[j] >> PACK_SHIFT], 1);
    __syncthreads();
    if (tid < 128) scn[tid] = cnt[tid];
    __syncthreads();
    for (int off = 1; off < 128; off <<= 1) {
        int tval = (tid < 128 && tid >= off) ? scn[tid - off] : 0;
        __syncthreads();
        if (tid < 128) scn[tid] += tval;
        __syncthreads();
    }
    if (tid < 128) {
        int rp = s + scn[tid] - cnt[tid];  // exclusive
        cur[tid] = rp;
        if (tid < nr) {
            row_ptr[lo + tid] = rp;
            dinv[lo + tid] = rsqrtf(1.0f + (float)cnt[tid]);  // +1 self-loop
        }
    }
    __syncthreads();
    for (int j = s + tid; j < e; j += 256) {
        unsigned int p = pair[j];
        int pos = atomicAdd(&cur[p >> PACK_SHIFT], 1);
        csr_col[pos] = (int)(p & PACK_MASK);
    }
}

// ---------------------------------------------------------------------------
// GEMM1 (barrier-free register accumulation): 64 rows/block, 1563 blocks.
// Lane (lrow=tid>>3, lkq=tid&7): owns rows {rbase+8t+lrow, t=0..7} and the
// 4-wide k-slice {c*32+4*lkq..+3} per chunk. Loads: per wave instr, 8 rows x
// 128B full lines, coalesced, consumed immediately from registers. acc[8][16]
// in VGPRs; NO __syncthreads in the K-loop -> pf/pg double-buffer prefetch is
// actually overlapped by the scheduler (R11 lesson: any barrier between
// prefetch-issue and compute drains vmcnt). W1T staged once to 8KB LDS; 16
// broadcast ds_read_b128 per chunk. Epilogue: 3-stage shfl_xor over lkq.
// ---------------------------------------------------------------------------
__global__ __launch_bounds__(64) void k_gemm1(
        const float* __restrict__ x, const float* __restrict__ w1t,
        const float* __restrict__ dinv, float* __restrict__ hn, int n) {
    __shared__ float4 wls[16 * 128];  // W1T as float4[16][128], 8KB
    const int tid = threadIdx.x;
    const int rbase = blockIdx.x * 64;
    const int lrow = tid >> 3, lkq = tid & 7;

    // stage W1T once (coalesced b128 global reads)
    #pragma unroll
    for (int i = 0; i < 32; ++i)
        wls[i * 64 + tid] = ((const float4*)w1t)[i * 64 + tid];
    __syncthreads();                  // only barrier in the kernel

    float acc[8][16];
    #pragma unroll
    for (int t = 0; t < 8; ++t)
        #pragma unroll
        for (int f = 0; f < 16; ++f) acc[t][f] = 0.f;

    float4 pf[8], pg[8];

#define LOADX(P, c)                                                          \
    {                                                                        \
        _Pragma("unroll")                                                    \
        for (int t = 0; t < 8; ++t) {                                        \
            int gr = rbase + t * 8 + lrow;                                   \
            (P)[t] = (gr < n)                                                \
                ? *(const float4*)(x + (size_t)gr * 512 + (c) * 32 + lkq * 4)\
                : make_float4(0.f, 0.f, 0.f, 0.f);                           \
        }                                                                    \
    }

#define COMPUTE(P, c)                                                        \
    {                                                                        \
        _Pragma("unroll")                                                    \
        for (int f = 0; f < 16; ++f) {                                       \
            float4 wv = wls[f * 128 + (c) * 8 + lkq];                        \
            _Pragma("unroll")                                                \
            for (int t = 0; t < 8; ++t) {                                    \
                acc[t][f] += (P)[t].x * wv.x + (P)[t].y * wv.y               \
                           + (P)[t].z * wv.z + (P)[t].w * wv.w;              \
            }                                                                \
        }                                                                    \
    }

    LOADX(pf, 0);
    for (int c = 0; c < 16; c += 2) {
        LOADX(pg, c + 1);             // prefetch odd chunk
        COMPUTE(pf, c);
        if (c + 2 < 16) LOADX(pf, c + 2);  // prefetch next even chunk
        COMPUTE(pg, c + 1);
    }
#undef LOADX
#undef COMPUTE

    // reduce over the 8 lkq lanes (masks 1,2,4)
    #pragma unroll
    for (int m = 1; m <= 4; m <<= 1)
        #pragma unroll
        for (int t = 0; t < 8; ++t)
            #pragma unroll
            for (int f = 0; f < 16; ++f)
                acc[t][f] += __shfl_xor(acc[t][f], m);

    // lanes lkq<4 store f-quad q==lkq for their 8 rows (static indexing per q)
    #pragma unroll
    for (int q = 0; q < 4; ++q) {
        if (lkq == q) {
            #pragma unroll
            for (int t = 0; t < 8; ++t) {
                int row = rbase + t * 8 + lrow;
                if (row < n) {
                    float d = dinv[row];
                    float4 v = make_float4(acc[t][4 * q + 0] * d,
                                           acc[t][4 * q + 1] * d,
                                           acc[t][4 * q + 2] * d,
                                           acc[t][4 * q + 3] * d);
                    *(float4*)(hn + (size_t)row * 16 + 4 * q) = v;
                }
            }
        }
    }
}

// ---------------------------------------------------------------------------
// Layer-1 aggregation + fused relu/b1/dinv: wave per node.
// Lane layout: slot = lane>>2 (16 edge slots), q = lane&3 (float4 of row).
// u[i] = relu(dinv[i]*(hn[i]+sum hn[col]) + b1) * dinv[i]
// ---------------------------------------------------------------------------
__global__ __launch_bounds__(256) void k_agg1(
        const float* __restrict__ hn, const int* __restrict__ row_ptr,
        const int* __restrict__ csr_col, const float* __restrict__ dinv,
        const float* __restrict__ b1, float* __restrict__ u, int n) {
    int wid = threadIdx.x >> 6, lane = threadIdx.x & 63;
    int i = blockIdx.x * 4 + wid;
    if (i >= n) return;
    int slot = lane >> 2, q = lane & 3;
    int start = row_ptr[i], end = row_ptr[i + 1];

    float4 acc = {0.f, 0.f, 0.f, 0.f};
    int j = start + slot;
    int c = (j < end) ? csr_col[j] : 0;
    while (j < end) {
        int jn = j + 16;
        int cn = (jn < end) ? csr_col[jn] : 0;   // prefetch next col
        float4 v = *(const float4*)(hn + (size_t)c * 16 + 4 * q);
        acc.x += v.x; acc.y += v.y; acc.z += v.z; acc.w += v.w;
        c = cn; j = jn;
    }
    #pragma unroll
    for (int off = 4; off < 64; off <<= 1) {
        acc.x += __shfl_xor(acc.x, off);
        acc.y += __shfl_xor(acc.y, off);
        acc.z += __shfl_xor(acc.z, off);
        acc.w += __shfl_xor(acc.w, off);
    }
    float d = dinv[i];
    float4 hs = *(const float4*)(hn + (size_t)i * 16 + 4 * q);
    float4 bb = *(const float4*)(b1 + 4 * q);
    float4 uo;
    uo.x = fmaxf((acc.x + hs.x) * d + bb.x, 0.f) * d;
    uo.y = fmaxf((acc.y + hs.y) * d + bb.y, 0.f) * d;
    uo.z = fmaxf((acc.z + hs.z) * d + bb.z, 0.f) * d;
    uo.w = fmaxf((acc.w + hs.w) * d + bb.w, 0.f) * d;
    if (lane < 4) *(float4*)(u + (size_t)i * 16 + 4 * q) = uo;  // 64B store
}

// ---------------------------------------------------------------------------
// Layer-2 aggregation (16-wide) + fused W2 GEMM + b2 + log_softmax.
// ---------------------------------------------------------------------------
__global__ __launch_bounds__(256) void k_agg2f(
        const float* __restrict__ u, const int* __restrict__ row_ptr,
        const int* __restrict__ csr_col, const float* __restrict__ dinv,
        const float* __restrict__ W2, const float* __restrict__ b2,
        float* __restrict__ out, int n) {
    __shared__ float w2s[640];
    int tid = threadIdx.x;
    if (tid < 160) ((float4*)w2s)[tid] = ((const float4*)W2)[tid];
    __syncthreads();

    int wid = tid >> 6, lane = tid & 63;
    int i = blockIdx.x * 4 + wid;
    if (i >= n) return;
    int slot = lane >> 2, q = lane & 3;
    int start = row_ptr[i], end = row_ptr[i + 1];

    float4 acc = {0.f, 0.f, 0.f, 0.f};
    int j = start + slot;
    int c = (j < end) ? csr_col[j] : 0;
    while (j < end) {
        int jn = j + 16;
        int cn = (jn < end) ? csr_col[jn] : 0;
        float4 v = *(const float4*)(u + (size_t)c * 16 + 4 * q);
        acc.x += v.x; acc.y += v.y; acc.z += v.z; acc.w += v.w;
        c = cn; j = jn;
    }
    #pragma unroll
    for (int off = 4; off < 64; off <<= 1) {
        acc.x += __shfl_xor(acc.x, off);
        acc.y += __shfl_xor(acc.y, off);
        acc.z += __shfl_xor(acc.z, off);
        acc.w += __shfl_xor(acc.w, off);
    }
    float d = dinv[i];
    float4 us = *(const float4*)(u + (size_t)i * 16 + 4 * q);
    float4 s4;
    s4.x = (acc.x + us.x) * d;
    s4.y = (acc.y + us.y) * d;
    s4.z = (acc.z + us.z) * d;
    s4.w = (acc.w + us.w) * d;

    // GEMM 16x40: lane j (<40) accumulates out[j]; broadcast s from lanes 0..3
    bool act = lane < 40;
    float o = 0.f;
    #pragma unroll
    for (int q2 = 0; q2 < 4; ++q2) {
        float sx = __shfl(s4.x, q2);
        float sy = __shfl(s4.y, q2);
        float sz = __shfl(s4.z, q2);
        float sw = __shfl(s4.w, q2);
        if (act) {
            o += sx * w2s[(4 * q2 + 0) * 40 + lane];
            o += sy * w2s[(4 * q2 + 1) * 40 + lane];
            o += sz * w2s[(4 * q2 + 2) * 40 + lane];
            o += sw * w2s[(4 * q2 + 3) * 40 + lane];
        }
    }
    float v = act ? (o + b2[lane]) : -INFINITY;
    float m = v;
    #pragma unroll
    for (int off = 1; off < 64; off <<= 1) m = fmaxf(m, __shfl_xor(m, off));
    float ex = act ? __expf(v - m) : 0.f;
    float s = ex;
    #pragma unroll
    for (int off = 1; off < 64; off <<= 1) s += __shfl_xor(s, off);
    float ls = __logf(s) + m;
    if (act) out[(size_t)i * 40 + lane] = v - ls;
}

extern "C" void kernel_launch(void* const* d_in, const int* in_sizes, int n_in,
                              void* d_out, int out_size, void* d_ws, size_t ws_size,
                              hipStream_t stream) {
    const float* x  = (const float*)d_in[0];
    const void*  ei = d_in[1];
    const float* W1 = (const float*)d_in[2];
    const float* b1 = (const float*)d_in[3];
    const float* W2 = (const float*)d_in[4];
    const float* b2 = (const float*)d_in[5];
    float* out = (float*)d_out;

    const int n = in_sizes[0] / 512;
    const int E = in_sizes[1] / 2;
    const int nbuck = (n + 127) >> BSHIFT;   // 128 rows/bucket (<=1024 buckets)

    // workspace layout (256B aligned blocks)
    char* w = (char*)d_ws;
    size_t off = 0;
    auto take = [&](size_t bytes) { void* p = w + off; off = (off + bytes + 255) & ~(size_t)255; return p; };
    int*   flag    = (int*)take(4);
    float* dinv    = (float*)take((size_t)n * 4);
    int*   row_ptr = (int*)take((size_t)(n + 1) * 4);
    int*   bcnt    = (int*)take(4096);
    int*   bbase   = (int*)take(4100);
    int*   bcur    = (int*)take(4096);
    float* w1t     = (float*)take(8192 * 4);
    float* hn      = (float*)take((size_t)n * 16 * 4);
    float* u       = (float*)take((size_t)n * 16 * 4);
    int*   csr_col = (int*)take((size_t)E * 4);
    unsigned int* pair = (unsigned int*)take((size_t)E * 4);
    (void)ws_size;

    const int nb4 = (n + 3) / 4;
    const int nbB = (E + CHUNK_E - 1) / CHUNK_E;
    const int nbG = (n + 63) / 64;

    k_detect   <<<1, 64, 0, stream>>>((const int*)ei, flag);
    k_zero     <<<(nbuck + 255) / 256, 256, 0, stream>>>(bcnt, nbuck);
    k_w1t      <<<32, 256, 0, stream>>>(W1, w1t);
    k_bhist    <<<nbB, 256, 0, stream>>>(ei, flag, bcnt, E, nbuck);
    k_bscan    <<<1, 1024, 0, stream>>>(bcnt, bbase, bcur, nbuck, E, row_ptr, n);
    k_bscatter <<<nbB, 256, 0, stream>>>(ei, flag, bcur, pair, E, nbuck);
    k_bsort2   <<<nbuck, 256, 0, stream>>>(pair, bbase, row_ptr, dinv, csr_col, n);
    k_gemm1    <<<nbG, 64, 0, stream>>>(x, w1t, dinv, hn, n);
    k_agg1     <<<nb4, 256, 0, stream>>>(hn, row_ptr, csr_col, dinv, b1, u, n);
    k_agg2f    <<<nb4, 256, 0, stream>>>(u, row_ptr, csr_col, dinv, W2, b2, out, n);
}